// Round 1
// baseline (243.315 us; speedup 1.0000x reference)
//
#include <hip/hip_runtime.h>
#include <math.h>

// Problem constants (from reference): B=8192 rows, F=3072 features, block=3.
#define BATCH 8192
#define FEAT  3072
#define NBLK  1024          // FEAT / 3
#define TPB   256           // threads per workgroup (one workgroup per row)
#define BPT   4             // blocks per thread = NBLK / TPB

__global__ __launch_bounds__(TPB, 4)
void moebius_kernel(const float* __restrict__ x,
                    const float* __restrict__ w,
                    float* __restrict__ out) {
    // LDS: stage full row of x and w (12 KB each). sx is overwritten in place
    // with y (safe: each 3-elem block is read+written only by its owning thread).
    __shared__ float sx[FEAT];
    __shared__ float sw[FEAT];
    __shared__ float swred[TPB / 64];

    const int row = blockIdx.x;
    const int tid = threadIdx.x;

    const float4* __restrict__ x4 = (const float4*)(x + (size_t)row * FEAT);
    const float4* __restrict__ w4 = (const float4*)(w + (size_t)row * FEAT);
    float4* sx4 = (float4*)sx;
    float4* sw4 = (float4*)sw;

    // Coalesced stage: 3072 floats = 768 float4 per array, 3 per thread.
    #pragma unroll
    for (int i = 0; i < 3; ++i) {
        sx4[tid + i * TPB] = x4[tid + i * TPB];
        sw4[tid + i * TPB] = w4[tid + i * TPB];
    }
    __syncthreads();

    float lsum = 0.0f;

    #pragma unroll
    for (int j = 0; j < BPT; ++j) {
        const int k = tid + j * TPB;   // block index within row
        const int base = 3 * k;        // stride-3 LDS read: 2-way bank aliasing (free)

        const float x0 = sx[base], x1 = sx[base + 1], x2 = sx[base + 2];
        const float w0 = sw[base], w1 = sw[base + 1], w2 = sw[base + 2];

        const float r2    = x0 * x0 + x1 * x1 + x2 * x2;
        const float r     = sqrtf(r2);
        const float inv_r = 1.0f / r;
        const float xn0 = x0 * inv_r, xn1 = x1 * inv_r, xn2 = x2 * inv_r;

        const float p0 = xn0 + w0, p1 = xn1 + w1, p2 = xn2 + w2;
        const float wns  = w0 * w0 + w1 * w1 + w2 * w2;
        const float xwns = p0 * p0 + p1 * p1 + p2 * p2;
        const float inv_xwns = 1.0f / xwns;
        const float c = (1.0f - wns) * inv_xwns;

        const float yn0 = c * p0 + w0;
        const float yn1 = c * p1 + w1;
        const float yn2 = c * p2 + w2;

        // y = r * yn  (write back into sx in place)
        sx[base]     = r * yn0;
        sx[base + 1] = r * yn1;
        sx[base + 2] = r * yn2;

        // Jacobian (analytic, d=3):
        //   J_ij = c*(delta_ij - xn_i*xn_j - (2/xwns)*p_i*(p_j - s*xn_j)) + yn_i*xn_j
        // where s = xn . p   (derived from reference; r cancels with dxn_dx's 1/r)
        const float s  = xn0 * p0 + xn1 * p1 + xn2 * p2;
        const float t2 = 2.0f * inv_xwns;
        const float q0 = p0 - s * xn0;
        const float q1 = p1 - s * xn1;
        const float q2 = p2 - s * xn2;

        const float J00 = c * (1.0f - xn0 * xn0 - t2 * p0 * q0) + yn0 * xn0;
        const float J01 = c * (       - xn0 * xn1 - t2 * p0 * q1) + yn0 * xn1;
        const float J02 = c * (       - xn0 * xn2 - t2 * p0 * q2) + yn0 * xn2;
        const float J10 = c * (       - xn1 * xn0 - t2 * p1 * q0) + yn1 * xn0;
        const float J11 = c * (1.0f - xn1 * xn1 - t2 * p1 * q1) + yn1 * xn1;
        const float J12 = c * (       - xn1 * xn2 - t2 * p1 * q2) + yn1 * xn2;
        const float J20 = c * (       - xn2 * xn0 - t2 * p2 * q0) + yn2 * xn0;
        const float J21 = c * (       - xn2 * xn1 - t2 * p2 * q1) + yn2 * xn1;
        const float J22 = c * (1.0f - xn2 * xn2 - t2 * p2 * q2) + yn2 * xn2;

        const float det = J00 * (J11 * J22 - J12 * J21)
                        - J01 * (J10 * J22 - J12 * J20)
                        + J02 * (J10 * J21 - J11 * J20);

        lsum += logf(fabsf(det));
    }

    __syncthreads();   // sx now holds y for the whole row

    // Coalesced y store.
    float4* y4 = (float4*)(out + (size_t)row * FEAT);
    #pragma unroll
    for (int i = 0; i < 3; ++i) {
        y4[tid + i * TPB] = sx4[tid + i * TPB];
    }

    // Row reduction of log|det|: wave shuffle (64 lanes) then cross-wave LDS.
    #pragma unroll
    for (int off = 32; off > 0; off >>= 1) {
        lsum += __shfl_down(lsum, off, 64);
    }
    const int lane = tid & 63;
    const int wave = tid >> 6;
    if (lane == 0) swred[wave] = lsum;
    __syncthreads();
    if (tid == 0) {
        float tot = swred[0] + swred[1] + swred[2] + swred[3];
        out[(size_t)BATCH * FEAT + row] = tot;
    }
}

extern "C" void kernel_launch(void* const* d_in, const int* in_sizes, int n_in,
                              void* d_out, int out_size, void* d_ws, size_t ws_size,
                              hipStream_t stream) {
    const float* x = (const float*)d_in[0];
    const float* w = (const float*)d_in[1];
    float* out = (float*)d_out;   // [B*F] y followed by [B] log_det_J

    moebius_kernel<<<BATCH, TPB, 0, stream>>>(x, w, out);
}

// Round 2
// 241.681 us; speedup vs baseline: 1.0068x; 1.0068x over previous
//
#include <hip/hip_runtime.h>
#include <math.h>

// Problem constants (from reference): B=8192 rows, F=3072 features, block=3.
#define BATCH 8192
#define FEAT  3072
#define NBLK  1024          // FEAT / 3
#define TPB   256           // one workgroup per row
#define BPT   4             // 3-elem blocks per thread = NBLK / TPB

// Analytic log|det J| for the d=3 Moebius block:
//   T(z) = w + (1-|w|^2)(z+w)/|z+w|^2  is conformal, DT = lambda*(I-2nn^T),
//   lambda = (1-|w|^2)/|z+w|^2. For y = r*T(x/r):
//   J = T(u)u^T + lambda*R*(I-uu^T),  det J = -lambda^{d-1} u^T R T(u),
//   and R*T(u) = -u exactly  =>  |det J| = lambda^{d-1} = lambda^2 (d=3).
//   log|det J| = 2*ln(lambda) = 2*ln2*log2(c), c = (1-wns)/xwns (computed for y anyway).

__global__ __launch_bounds__(TPB, 8)
void moebius_kernel(const float* __restrict__ x,
                    const float* __restrict__ w,
                    float* __restrict__ out) {
    __shared__ float swred[TPB / 64];

    const int row = blockIdx.x;
    const int tid = threadIdx.x;
    const size_t rb = (size_t)row * FEAT;

    float lsum = 0.0f;   // accumulates log2(c)

    #pragma unroll
    for (int j = 0; j < BPT; ++j) {
        const int k = tid + j * TPB;            // block index within row
        const float* __restrict__ xp = x + rb + 3 * k;   // 12 B/lane, contiguous per wave
        const float* __restrict__ wp = w + rb + 3 * k;

        const float x0 = xp[0], x1 = xp[1], x2 = xp[2];
        const float w0 = wp[0], w1 = wp[1], w2 = wp[2];

        const float r2   = x0 * x0 + x1 * x1 + x2 * x2;
        const float invr = __builtin_amdgcn_rsqf(r2);     // 1/sqrt
        const float r    = r2 * invr;                     // |x|

        const float p0 = x0 * invr + w0;
        const float p1 = x1 * invr + w1;
        const float p2 = x2 * invr + w2;

        const float wns  = w0 * w0 + w1 * w1 + w2 * w2;
        const float xwns = p0 * p0 + p1 * p1 + p2 * p2;
        const float c    = (1.0f - wns) * __builtin_amdgcn_rcpf(xwns);  // > 0 (|w|<1)

        float* __restrict__ yp = out + rb + 3 * k;
        yp[0] = r * (c * p0 + w0);
        yp[1] = r * (c * p1 + w1);
        yp[2] = r * (c * p2 + w2);

        lsum += __builtin_amdgcn_logf(c);       // log2(c)
    }

    // Row reduction: wave shuffle (64 lanes) then cross-wave LDS.
    #pragma unroll
    for (int off = 32; off > 0; off >>= 1) {
        lsum += __shfl_down(lsum, off, 64);
    }
    const int lane = tid & 63;
    const int wave = tid >> 6;
    if (lane == 0) swred[wave] = lsum;
    __syncthreads();
    if (tid == 0) {
        // log|det| sum = 2*ln2 * sum(log2 c)
        const float tot = (swred[0] + swred[1] + swred[2] + swred[3]) * 1.3862943611f;
        out[(size_t)BATCH * FEAT + row] = tot;
    }
}

extern "C" void kernel_launch(void* const* d_in, const int* in_sizes, int n_in,
                              void* d_out, int out_size, void* d_ws, size_t ws_size,
                              hipStream_t stream) {
    const float* x = (const float*)d_in[0];
    const float* w = (const float*)d_in[1];
    float* out = (float*)d_out;   // [B*F] y followed by [B] log_det_J

    moebius_kernel<<<BATCH, TPB, 0, stream>>>(x, w, out);
}

// Round 4
// 240.470 us; speedup vs baseline: 1.0118x; 1.0050x over previous
//
#include <hip/hip_runtime.h>
#include <math.h>

// B=8192 rows, F=3072 features, block=3. One workgroup per row.
// Each thread owns 4 consecutive 3-elem blocks = 12 contiguous floats,
// loaded as 3 float4 per input (all 6 loads issued before any compute ->
// 6 KB/wave in flight), computed, stored as 3 float4.
#define BATCH 8192
#define FEAT  3072
#define TPB   256

// Analytic log|det J| for the d=3 Moebius block:
//   T(z) = w + (1-|w|^2)(z+w)/|z+w|^2 is conformal, DT = lambda*(I-2nn^T),
//   lambda = (1-|w|^2)/|z+w|^2 = c. For y = r*T(x/r): |det J| = c^(d-1) = c^2.
//   sum log|det| = 2*ln2 * sum log2(c).

__global__ __launch_bounds__(TPB, 8)
void moebius_kernel(const float* __restrict__ x,
                    const float* __restrict__ w,
                    float* __restrict__ out) {
    __shared__ float swred[TPB / 64];

    const int row = blockIdx.x;
    const int tid = threadIdx.x;
    const size_t base = (size_t)row * FEAT + 12 * tid;

    const float4* __restrict__ x4 = (const float4*)(x + base);
    const float4* __restrict__ w4 = (const float4*)(w + base);

    // Six independent 16B loads, all issued up front.
    const float4 xa = x4[0], xb = x4[1], xc = x4[2];
    const float4 wa = w4[0], wb = w4[1], wc = w4[2];

    const float X[12] = {xa.x, xa.y, xa.z, xa.w, xb.x, xb.y, xb.z, xb.w,
                         xc.x, xc.y, xc.z, xc.w};
    const float W[12] = {wa.x, wa.y, wa.z, wa.w, wb.x, wb.y, wb.z, wb.w,
                         wc.x, wc.y, wc.z, wc.w};
    float Y[12];

    float lsum = 0.0f;   // accumulates log2(c)

    #pragma unroll
    for (int j = 0; j < 4; ++j) {
        const float x0 = X[3 * j], x1 = X[3 * j + 1], x2 = X[3 * j + 2];
        const float w0 = W[3 * j], w1 = W[3 * j + 1], w2 = W[3 * j + 2];

        // fmaxf guard: numerically inert for real inputs (P(r2<1e-30)~0) but
        // blocks the only inf->NaN propagation path (rsq(0)=inf, 0*inf=NaN).
        const float r2   = fmaxf(x0 * x0 + x1 * x1 + x2 * x2, 1e-30f);
        const float invr = __builtin_amdgcn_rsqf(r2);   // 1/|x|
        const float r    = r2 * invr;                   // |x|

        const float p0 = x0 * invr + w0;
        const float p1 = x1 * invr + w1;
        const float p2 = x2 * invr + w2;

        const float wns  = w0 * w0 + w1 * w1 + w2 * w2;
        const float xwns = fmaxf(p0 * p0 + p1 * p1 + p2 * p2, 1e-30f);
        const float c    = (1.0f - wns) * __builtin_amdgcn_rcpf(xwns);  // > 0

        Y[3 * j]     = r * (c * p0 + w0);
        Y[3 * j + 1] = r * (c * p1 + w1);
        Y[3 * j + 2] = r * (c * p2 + w2);

        lsum += __builtin_amdgcn_logf(c);   // log2(c)
    }

    float4* __restrict__ y4 = (float4*)(out + base);
    y4[0] = make_float4(Y[0], Y[1], Y[2],  Y[3]);
    y4[1] = make_float4(Y[4], Y[5], Y[6],  Y[7]);
    y4[2] = make_float4(Y[8], Y[9], Y[10], Y[11]);

    // Row reduction: wave shuffle (64 lanes) then cross-wave LDS.
    #pragma unroll
    for (int off = 32; off > 0; off >>= 1) {
        lsum += __shfl_down(lsum, off, 64);
    }
    const int lane = tid & 63;
    const int wave = tid >> 6;
    if (lane == 0) swred[wave] = lsum;
    __syncthreads();
    if (tid == 0) {
        const float tot = (swred[0] + swred[1] + swred[2] + swred[3]) * 1.3862943611f;
        out[(size_t)BATCH * FEAT + row] = tot;   // 2*ln2 * sum(log2 c)
    }
}

extern "C" void kernel_launch(void* const* d_in, const int* in_sizes, int n_in,
                              void* d_out, int out_size, void* d_ws, size_t ws_size,
                              hipStream_t stream) {
    const float* x = (const float*)d_in[0];
    const float* w = (const float*)d_in[1];
    float* out = (float*)d_out;   // [B*F] y followed by [B] log_det_J

    moebius_kernel<<<BATCH, TPB, 0, stream>>>(x, w, out);
}